// Round 1
// 270.435 us; speedup vs baseline: 1.1435x; 1.1435x over previous
//
#include <hip/hip_runtime.h>
#include <hip/hip_bf16.h>
#include <hip/hip_fp16.h>

// SpatialAttention: B=32, C=273, T=3000, O=270, D=2048. fp32 in, fp32 out.
#define NB 32
#define NC 273
#define NT 3000
#define NO 270
#define ND 2048
#define CP 288  // C padded to 9*32 for out-GEMM K dimension

typedef _Float16 f16x8 __attribute__((ext_vector_type(8)));
typedef float f32x4 __attribute__((ext_vector_type(4)));

// Workspace layout (bytes):
//   [0,        55,296,000)  X^T   _Float16 [NB][NT][CP]
//   [55296000, 64,730,880)  scores float   [NB][NO][NC]
//   [64730880, 69,707,520)  W     _Float16 [NB][NO][CP]  (softmaxed weights, zero-padded)
//   [69707520, 70,813,440)  headsh _Float16 [NO][ND]
// Peak ws = 70,813,440 B (unchanged from previous version).
#define S_OFF 55296000UL
#define W_OFF 64730880UL
#define H_OFF 69707520UL

__device__ __forceinline__ unsigned short f2h_bits(float f) {
  _Float16 h = (_Float16)f;
  unsigned short u;
  __builtin_memcpy(&u, &h, 2);
  return u;
}

// ---------------------------------------------------------------------------
// heads fp32 -> fp16. 270 blocks x 256 thr x 8 elems (exact).
// ---------------------------------------------------------------------------
__global__ void heads_cvt_kernel(const float* __restrict__ heads,
                                 _Float16* __restrict__ hh) {
  const size_t idx = ((size_t)blockIdx.x * 256 + threadIdx.x) * 8;
  const float4 a = *reinterpret_cast<const float4*>(heads + idx);
  const float4 c = *reinterpret_cast<const float4*>(heads + idx + 4);
  f16x8 v;
  v[0] = (_Float16)a.x; v[1] = (_Float16)a.y; v[2] = (_Float16)a.z; v[3] = (_Float16)a.w;
  v[4] = (_Float16)c.x; v[5] = (_Float16)c.y; v[6] = (_Float16)c.z; v[7] = (_Float16)c.w;
  *reinterpret_cast<f16x8*>(hh + idx) = v;
}

// ---------------------------------------------------------------------------
// Fused mid kernel: two independent roles in one launch so the VALU/MFMA-bound
// scores blocks (low blockIdx, dispatched first) overlap the HBM-bound
// transpose blocks.
//
// Role 1 (gid < 800): scores[b,o,c] = sum_d heads[o,d]*emb[b,c,d], with the
//   emb B-tile GENERATED in-register: emb phase is naturally in revolutions,
//   so v_sin_f32 (sin(2*pi*x)) after fract gives sin; cos = sin(x+0.25 rev).
//   No global emb traffic at all. Tile 64(o) x 64(c), K-step 64, 4 waves 2x2.
// Role 2: brain fp32 [b][c][t] -> X^T fp16 [b][t][CP], 64x64 tiles,
//   16 elems/thread, zero-padded c>=273.
// ---------------------------------------------------------------------------
#define SC_BLOCKS 800            // 5 c-tiles x 5 o-tiles x 32 b
#define TR_TX 47                 // ceil(3000/64)
#define TR_BLOCKS (TR_TX * 5 * NB)

__global__ void mid_kernel(const _Float16* __restrict__ hh,
                           const float* __restrict__ layout,
                           const float* __restrict__ brain,
                           float* __restrict__ scores,
                           _Float16* __restrict__ xh) {
  __shared__ __align__(16) char smem[18432];  // scores: 2x 64x72 fp16; transpose: 64x68 fp32
  const int gid = blockIdx.x;
  const int tid = threadIdx.x;

  if (gid < SC_BLOCKS) {
    // ---------------- scores role ----------------
    _Float16 (*As)[72] = reinterpret_cast<_Float16 (*)[72]>(smem);
    _Float16 (*Bs)[72] = reinterpret_cast<_Float16 (*)[72]>(smem + 9216);
    const int b = gid / 25;
    const int rem = gid % 25;
    const int o0 = (rem / 5) * 64;
    const int c0 = (rem % 5) * 64;
    const int lane = tid & 63, w = tid >> 6;
    const int wm = (w >> 1) * 32, wn = (w & 1) * 32;
    const int ln = lane & 15, quad = lane >> 4;
    const int sr = tid >> 2;        // staging row 0..63 (o for A, c for B)
    const int sk = (tid & 3) * 16;  // k-chunk offset (halves)

    // Per-thread channel position for B-tile generation.
    const int ch = c0 + sr;
    float px = 0.f, py = 0.f;
    if (ch < NC) {
      const float inv = 1.0f / 1.2f;
      const float* lp = layout + ((size_t)b * NC + ch) * 2;
      px = (lp[0] + 0.1f) * inv;
      py = (lp[1] + 0.1f) * inv;
    }

    f32x4 acc[2][2] = {};

    for (int k0 = 0; k0 < ND; k0 += 64) {
      {  // A-tile staging (heads fp16, L2-resident)
        const int o = o0 + sr;
        uint4 u0 = {0, 0, 0, 0}, u1 = {0, 0, 0, 0};
        if (o < NO) {
          const uint4* p = reinterpret_cast<const uint4*>(hh + (size_t)o * ND + k0 + sk);
          u0 = p[0]; u1 = p[1];
        }
        *reinterpret_cast<uint4*>(&As[sr][sk]) = u0;
        *reinterpret_cast<uint4*>(&As[sr][sk + 8]) = u1;
      }
      {  // B-tile generation: 16 consecutive k share i (k-chunk of 16 never
         // crosses a multiple of 32), so base + py*s walks j. Phase in
         // revolutions; fract then v_sin. cos folded via +0.25 rev.
        const int kg = k0 + sk;      // multiple of 16
        const int dd = kg & 1023;    // multiple of 16
        const float base = px * (float)(dd >> 5) + py * (float)(dd & 31)
                         + ((kg < 1024) ? 0.0f : 0.25f);
        f16x8 h0, h1;
#pragma unroll
        for (int s = 0; s < 8; ++s) {
          float ph = base + py * (float)s;
          ph -= floorf(ph);
          h0[s] = (_Float16)__builtin_amdgcn_sinf(ph);
        }
#pragma unroll
        for (int s = 0; s < 8; ++s) {
          float ph = base + py * (float)(s + 8);
          ph -= floorf(ph);
          h1[s] = (_Float16)__builtin_amdgcn_sinf(ph);
        }
        *reinterpret_cast<f16x8*>(&Bs[sr][sk]) = h0;
        *reinterpret_cast<f16x8*>(&Bs[sr][sk + 8]) = h1;
      }
      __syncthreads();
#pragma unroll
      for (int ks = 0; ks < 64; ks += 32) {
        const int kf = ks + quad * 8;
        const f16x8 a0 = *reinterpret_cast<const f16x8*>(&As[wm + ln][kf]);
        const f16x8 a1 = *reinterpret_cast<const f16x8*>(&As[wm + 16 + ln][kf]);
        const f16x8 b0 = *reinterpret_cast<const f16x8*>(&Bs[wn + ln][kf]);
        const f16x8 b1 = *reinterpret_cast<const f16x8*>(&Bs[wn + 16 + ln][kf]);
        acc[0][0] = __builtin_amdgcn_mfma_f32_16x16x32_f16(a0, b0, acc[0][0], 0, 0, 0);
        acc[0][1] = __builtin_amdgcn_mfma_f32_16x16x32_f16(a0, b1, acc[0][1], 0, 0, 0);
        acc[1][0] = __builtin_amdgcn_mfma_f32_16x16x32_f16(a1, b0, acc[1][0], 0, 0, 0);
        acc[1][1] = __builtin_amdgcn_mfma_f32_16x16x32_f16(a1, b1, acc[1][1], 0, 0, 0);
      }
      __syncthreads();
    }

    float* sB = scores + (size_t)b * NO * NC;
#pragma unroll
    for (int i = 0; i < 2; ++i) {
      const int ob = o0 + wm + 16 * i + quad * 4;
#pragma unroll
      for (int j = 0; j < 2; ++j) {
        const int cc = c0 + wn + 16 * j + ln;
        if (cc >= NC) continue;
#pragma unroll
        for (int r = 0; r < 4; ++r) {
          const int o = ob + r;
          if (o < NO) sB[(size_t)o * NC + cc] = acc[i][j][r];
        }
      }
    }
  } else {
    // ---------------- transpose role ----------------
    float (*tile)[68] = reinterpret_cast<float (*)[68]>(smem);
    const int id = gid - SC_BLOCKS;
    const int tx = id % TR_TX;
    const int r2 = id / TR_TX;
    const int c0 = (r2 % 5) * 64;
    const int b = r2 / 5;
    const int t0 = tx * 64;
    {
      const int cl = tid >> 2;
      const int tl = (tid & 3) * 16;
      const int c = c0 + cl;
      const int t = t0 + tl;
      float4 v0 = {0.f, 0.f, 0.f, 0.f}, v1 = v0, v2 = v0, v3 = v0;
      if (c < NC) {
        const float* p = brain + ((size_t)b * NC + c) * NT + t;
        if (t + 15 < NT) {
          v0 = *reinterpret_cast<const float4*>(p + 0);
          v1 = *reinterpret_cast<const float4*>(p + 4);
          v2 = *reinterpret_cast<const float4*>(p + 8);
          v3 = *reinterpret_cast<const float4*>(p + 12);
        } else {
          float tmp[16];
#pragma unroll
          for (int e = 0; e < 16; ++e) tmp[e] = (t + e < NT) ? p[e] : 0.f;
          v0.x = tmp[0];  v0.y = tmp[1];  v0.z = tmp[2];  v0.w = tmp[3];
          v1.x = tmp[4];  v1.y = tmp[5];  v1.z = tmp[6];  v1.w = tmp[7];
          v2.x = tmp[8];  v2.y = tmp[9];  v2.z = tmp[10]; v2.w = tmp[11];
          v3.x = tmp[12]; v3.y = tmp[13]; v3.z = tmp[14]; v3.w = tmp[15];
        }
      }
      *reinterpret_cast<float4*>(&tile[cl][tl + 0]) = v0;
      *reinterpret_cast<float4*>(&tile[cl][tl + 4]) = v1;
      *reinterpret_cast<float4*>(&tile[cl][tl + 8]) = v2;
      *reinterpret_cast<float4*>(&tile[cl][tl + 12]) = v3;
    }
    __syncthreads();
    {
      const int tl = tid >> 2;
      const int cl = (tid & 3) * 16;
      const int t = t0 + tl;
      if (t < NT && (c0 + cl) < CP) {
        unsigned short h[16];
#pragma unroll
        for (int s = 0; s < 16; ++s) h[s] = f2h_bits(tile[cl + s][tl]);
        uint4 u0, u1;
        u0.x = (unsigned)h[0]  | ((unsigned)h[1] << 16);
        u0.y = (unsigned)h[2]  | ((unsigned)h[3] << 16);
        u0.z = (unsigned)h[4]  | ((unsigned)h[5] << 16);
        u0.w = (unsigned)h[6]  | ((unsigned)h[7] << 16);
        u1.x = (unsigned)h[8]  | ((unsigned)h[9] << 16);
        u1.y = (unsigned)h[10] | ((unsigned)h[11] << 16);
        u1.z = (unsigned)h[12] | ((unsigned)h[13] << 16);
        u1.w = (unsigned)h[14] | ((unsigned)h[15] << 16);
        _Float16* q = xh + ((size_t)b * NT + t) * CP + c0 + cl;
        *reinterpret_cast<uint4*>(q + 0) = u0;
        *reinterpret_cast<uint4*>(q + 8) = u1;
      }
    }
  }
}

// ---------------------------------------------------------------------------
// Row softmax over C=273, fp32 in -> fp16 weights out, zero-padded to CP=288.
// One wave per (b,o) row. grid = 8640/4, block 256.
// ---------------------------------------------------------------------------
__global__ void softmax_kernel(const float* __restrict__ sc,
                               _Float16* __restrict__ wq) {
  const int row = blockIdx.x * 4 + (threadIdx.x >> 6);
  const int lane = threadIdx.x & 63;
  const float* p = sc + (size_t)row * NC;
  _Float16* q = wq + (size_t)row * CP;
  float v[5];
  float m = -3.0e38f;
#pragma unroll
  for (int k = 0; k < 5; ++k) {
    const int c = lane + k * 64;
    v[k] = (c < NC) ? p[c] : -3.0e38f;
    m = fmaxf(m, v[k]);
  }
#pragma unroll
  for (int off = 32; off > 0; off >>= 1) m = fmaxf(m, __shfl_xor(m, off));
  float s = 0.f;
#pragma unroll
  for (int k = 0; k < 5; ++k) {
    v[k] = expf(v[k] - m);
    s += v[k];
  }
#pragma unroll
  for (int off = 32; off > 0; off >>= 1) s += __shfl_xor(s, off);
  const float r = 1.0f / s;
#pragma unroll
  for (int k = 0; k < 5; ++k) {
    const int c = lane + k * 64;
    if (c < NC) q[c] = (_Float16)(v[k] * r);
    else if (c < CP) q[c] = (_Float16)0.f;
  }
}

// ---------------------------------------------------------------------------
// out[b,o,t] = sum_c W[b,o,c]*X^T[b,t,c]. MFMA NT-GEMM.
// Tile M=64(o) x N=128(t), K=CP=288, K-step 32 (9 iters). 4 waves 2x2; each
// wave 32x64 via 2x4 mfma tiles. LDS pitch 40 halves.
// grid = (24 t-tiles, 5 o-tiles, 32 b); x=t innermost: 24%8==0 keeps the 5
// o-blocks of a given (t,b) on one XCD for X^T L2 reuse.
// ---------------------------------------------------------------------------
__global__ void out_kernel(const _Float16* __restrict__ wq,
                           const _Float16* __restrict__ xh,
                           float* __restrict__ out) {
  __shared__ _Float16 As[64][40];
  __shared__ _Float16 Bs[128][40];
  const int b = blockIdx.z, o0 = blockIdx.y * 64, t0 = blockIdx.x * 128;
  const int tid = threadIdx.x;
  const int lane = tid & 63, w = tid >> 6;
  const int wm = (w >> 1) * 32, wn = (w & 1) * 64;
  const int ln = lane & 15, quad = lane >> 4;
  const _Float16* Wb = wq + (size_t)b * NO * CP;
  const _Float16* Xb = xh + (size_t)b * NT * CP;

  const int ar = tid >> 2, ak = (tid & 3) * 8;   // A staging: 64 rows x 8 halves
  const int br = tid >> 1, bk = (tid & 1) * 16;  // B staging: 128 rows x 16 halves

  f32x4 acc[2][4] = {};

  for (int k0 = 0; k0 < CP; k0 += 32) {
    {
      const int o = o0 + ar;
      uint4 u = {0, 0, 0, 0};
      if (o < NO) u = *reinterpret_cast<const uint4*>(Wb + (size_t)o * CP + k0 + ak);
      *reinterpret_cast<uint4*>(&As[ar][ak]) = u;
    }
    {
      const int t = t0 + br;
      uint4 u0 = {0, 0, 0, 0}, u1 = {0, 0, 0, 0};
      if (t < NT) {
        const uint4* p = reinterpret_cast<const uint4*>(Xb + (size_t)t * CP + k0 + bk);
        u0 = p[0]; u1 = p[1];
      }
      *reinterpret_cast<uint4*>(&Bs[br][bk]) = u0;
      *reinterpret_cast<uint4*>(&Bs[br][bk + 8]) = u1;
    }
    __syncthreads();
    {
      const int kf = quad * 8;
      const f16x8 a0 = *reinterpret_cast<const f16x8*>(&As[wm + ln][kf]);
      const f16x8 a1 = *reinterpret_cast<const f16x8*>(&As[wm + 16 + ln][kf]);
#pragma unroll
      for (int j = 0; j < 4; ++j) {
        const f16x8 bj = *reinterpret_cast<const f16x8*>(&Bs[wn + 16 * j + ln][kf]);
        acc[0][j] = __builtin_amdgcn_mfma_f32_16x16x32_f16(a0, bj, acc[0][j], 0, 0, 0);
        acc[1][j] = __builtin_amdgcn_mfma_f32_16x16x32_f16(a1, bj, acc[1][j], 0, 0, 0);
      }
    }
    __syncthreads();
  }

  float* oB = out + (size_t)b * NO * NT;
#pragma unroll
  for (int i = 0; i < 2; ++i) {
    const int ob = o0 + wm + 16 * i + quad * 4;
#pragma unroll
    for (int j = 0; j < 4; ++j) {
      const int t = t0 + wn + 16 * j + ln;
      if (t >= NT) continue;
#pragma unroll
      for (int r = 0; r < 4; ++r) {
        const int o = ob + r;
        if (o < NO) oB[(size_t)o * NT + t] = acc[i][j][r];
      }
    }
  }
}

extern "C" void kernel_launch(void* const* d_in, const int* in_sizes, int n_in,
                              void* d_out, int out_size, void* d_ws, size_t ws_size,
                              hipStream_t stream) {
  const float* brain = (const float*)d_in[0];   // [32,273,3000]
  const float* layout = (const float*)d_in[1];  // [32,273,2]
  const float* heads = (const float*)d_in[2];   // [270,2048]
  for (int i = 0; i < n_in; ++i) {
    if (in_sizes[i] == NB * NC * NT) brain = (const float*)d_in[i];
    else if (in_sizes[i] == NB * NC * 2) layout = (const float*)d_in[i];
    else if (in_sizes[i] == NO * ND) heads = (const float*)d_in[i];
  }
  float* out = (float*)d_out;  // [32,270,3000]

  _Float16* xh = (_Float16*)d_ws;                    // [NB][NT][CP]
  float* scores = (float*)((char*)d_ws + S_OFF);     // [NB][NO][NC]
  _Float16* wq = (_Float16*)((char*)d_ws + W_OFF);   // [NB][NO][CP]
  _Float16* hh = (_Float16*)((char*)d_ws + H_OFF);   // [NO][ND]

  heads_cvt_kernel<<<NO, 256, 0, stream>>>(heads, hh);
  mid_kernel<<<SC_BLOCKS + TR_BLOCKS, 256, 0, stream>>>(hh, layout, brain, scores, xh);
  softmax_kernel<<<(NB * NO) / 4, 256, 0, stream>>>(scores, wq);
  out_kernel<<<dim3((NT + 127) / 128, 5, NB), 256, 0, stream>>>(wq, xh, out);
}